// Round 3
// baseline (5636.503 us; speedup 1.0000x reference)
//
#include <hip/hip_runtime.h>

#define T_STEPS 512
#define D_IN    32
#define H       64
#define NB      4     // batch elements per block

// ---- DPP cross-lane add: sum over the 4 lanes of each quad (chunk id = lane&3) ----
template<int CTRL>
__device__ __forceinline__ float dpp_add(float v) {
    int m = __builtin_amdgcn_update_dpp(0, __float_as_int(v), CTRL, 0xf, 0xf, true);
    return v + __int_as_float(m);
}
__device__ __forceinline__ float red4(float v) {
    v = dpp_add<0xB1>(v);   // quad_perm [1,0,3,2] : + lane^1
    v = dpp_add<0x4E>(v);   // quad_perm [2,3,0,1] : + lane^2
    return v;
}

__device__ __forceinline__ float sigf(float x) {
    return 1.0f / (1.0f + __expf(-x));
}
__device__ __forceinline__ float tanhf_(float x) {
    float e = __expf(2.0f * x);
    return 1.0f - 2.0f / (e + 1.0f);
}

__global__ __launch_bounds__(1024, 4)
void lstm2_fused(const float* __restrict__ x,
                 const float* __restrict__ Wih0, const float* __restrict__ Whh0,
                 const float* __restrict__ bih0, const float* __restrict__ bhh0,
                 const float* __restrict__ Wih1, const float* __restrict__ Whh1,
                 const float* __restrict__ bih1, const float* __restrict__ bhh1,
                 const float* __restrict__ Wfc,  const float* __restrict__ bfc,
                 float* __restrict__ out)
{
    // L0 input: vin[b] = { x_t (32) , h0 (64) } contiguous.
    //   chunk c reads float4 at 24c+4q -> bank-quads {0,24,16,8}+q : conflict-free
    __shared__ __align__(16) float vin[NB][96];
    // L1 input: u1[b][c][36] = chunk c holds k in [32c, 32c+32), +4 pad floats.
    //   float4 at [c][4q] -> bank-quads {0,4,8,12}+q : conflict-free
    __shared__ __align__(16) float u1[NB][4][36];
    __shared__ __align__(16) float g0buf[NB][256];
    __shared__ __align__(16) float g1buf[NB][256];

    const int tid  = threadIdx.x;
    const int b0   = blockIdx.x * NB;
    const int lane = tid & 63;
    const int c    = lane & 3;                       // K-chunk id
    const bool isL0 = tid < 512;
    const int rg   = (isL0 ? tid : tid - 512) >> 2;  // row-pair 0..127
    const int r0a  = 2 * rg;                         // rows r0a, r0a+1

    // ---- per-thread weights: 2 rows x 1 chunk, as float4s (L0: 12, L1: 16) ----
    float4 wf[16];
    if (isL0) {
#pragma unroll
        for (int q = 0; q < 6; ++q)
#pragma unroll
            for (int rr = 0; rr < 2; ++rr) {
                int r = r0a + rr;
                float t[4];
#pragma unroll
                for (int e = 0; e < 4; ++e) {
                    int k = 24 * c + 4 * q + e;
                    t[e] = (k < 32) ? Wih0[r * D_IN + k] : Whh0[r * H + (k - 32)];
                }
                wf[2 * q + rr] = make_float4(t[0], t[1], t[2], t[3]);
            }
    } else {
#pragma unroll
        for (int q = 0; q < 8; ++q)
#pragma unroll
            for (int rr = 0; rr < 2; ++rr) {
                int r = r0a + rr;
                float t[4];
#pragma unroll
                for (int e = 0; e < 4; ++e) {
                    int k = 32 * c + 4 * q + e;
                    t[e] = (k < 64) ? Wih1[r * H + k] : Whh1[r * H + (k - 64)];
                }
                wf[2 * q + rr] = make_float4(t[0], t[1], t[2], t[3]);
            }
    }

    // ---- phase-C state owners ----
    // h0 states: threads [0,256)  (b = tid>>6, j = tid&63)
    // h1 states: threads [512,768)
    // x staging: threads [768,896)
    const int jst = tid & 63;
    const int bst = (tid >> 6) & 3;
    float bi = 0.f, bff = 0.f, bg = 0.f, bo = 0.f, cst = 0.f;
    if (tid < 256) {
        bi  = bih0[jst]       + bhh0[jst];
        bff = bih0[64 + jst]  + bhh0[64 + jst];
        bg  = bih0[128 + jst] + bhh0[128 + jst];
        bo  = bih0[192 + jst] + bhh0[192 + jst];
    } else if (tid >= 512 && tid < 768) {
        bi  = bih1[jst]       + bhh1[jst];
        bff = bih1[64 + jst]  + bhh1[64 + jst];
        bg  = bih1[128 + jst] + bhh1[128 + jst];
        bo  = bih1[192 + jst] + bhh1[192 + jst];
    }

    // ---- init: zero h-state LDS, stage x_0 ----
    if (tid < 256) vin[tid >> 6][32 + (tid & 63)] = 0.f;
    if (tid < 576) ((float*)u1)[tid] = 0.f;          // NB*4*36 = 576 (pads too)
    if (tid >= 768 && tid < 896) {
        int t2 = tid - 768, b = t2 >> 5, k = t2 & 31;
        vin[b][k] = x[(size_t)(b0 + b) * T_STEPS * D_IN + k];
    }
    __syncthreads();

    for (int it = 0; it <= T_STEPS; ++it) {
        // register-prefetch x_{it+1}
        float xpre = 0.f;
        const bool havex = (tid >= 768 && tid < 896) && (it + 1 < T_STEPS);
        if (havex) {
            int t2 = tid - 768, b = t2 >> 5, k = t2 & 31;
            xpre = x[(size_t)(b0 + b) * T_STEPS * D_IN + (size_t)(it + 1) * D_IN + k];
        }

        // ---- phase A: chunked gate matvecs, q-outer / b-inner ----
        if (isL0) {
            if (it < T_STEPS) {
                float acc0[NB] = {0.f, 0.f, 0.f, 0.f};
                float acc1[NB] = {0.f, 0.f, 0.f, 0.f};
#pragma unroll
                for (int q = 0; q < 6; ++q) {
                    float4 wA = wf[2 * q], wB = wf[2 * q + 1];
#pragma unroll
                    for (int b = 0; b < NB; ++b) {
                        float4 v = *(const float4*)&vin[b][24 * c + 4 * q];
                        acc0[b] += wA.x * v.x + wA.y * v.y + wA.z * v.z + wA.w * v.w;
                        acc1[b] += wB.x * v.x + wB.y * v.y + wB.z * v.z + wB.w * v.w;
                    }
                }
#pragma unroll
                for (int b = 0; b < NB; ++b) {
                    float a0 = red4(acc0[b]);
                    float a1 = red4(acc1[b]);
                    if (c == 0) {
                        float2 g2 = make_float2(a0, a1);
                        *(float2*)&g0buf[b][r0a] = g2;
                    }
                }
            }
        } else {
            if (it >= 1) {
                float acc0[NB] = {0.f, 0.f, 0.f, 0.f};
                float acc1[NB] = {0.f, 0.f, 0.f, 0.f};
#pragma unroll
                for (int q = 0; q < 8; ++q) {
                    float4 wA = wf[2 * q], wB = wf[2 * q + 1];
#pragma unroll
                    for (int b = 0; b < NB; ++b) {
                        float4 v = *(const float4*)&u1[b][c][4 * q];
                        acc0[b] += wA.x * v.x + wA.y * v.y + wA.z * v.z + wA.w * v.w;
                        acc1[b] += wB.x * v.x + wB.y * v.y + wB.z * v.z + wB.w * v.w;
                    }
                }
#pragma unroll
                for (int b = 0; b < NB; ++b) {
                    float a0 = red4(acc0[b]);
                    float a1 = red4(acc1[b]);
                    if (c == 0) {
                        float2 g2 = make_float2(a0, a1);
                        *(float2*)&g1buf[b][r0a] = g2;
                    }
                }
            }
        }
        __syncthreads();

        // ---- phase C: cell updates + x commit ----
        if (tid < 256) {
            if (it < T_STEPS) {
                float gi = g0buf[bst][jst]       + bi;
                float gf = g0buf[bst][64 + jst]  + bff;
                float gg = g0buf[bst][128 + jst] + bg;
                float go = g0buf[bst][192 + jst] + bo;
                float cc = sigf(gf) * cst + sigf(gi) * tanhf_(gg);
                cst = cc;
                float hh = sigf(go) * tanhf_(cc);
                vin[bst][32 + jst]           = hh;   // L0's next-step input
                u1[bst][jst >> 5][jst & 31]  = hh;   // L1 input chunk (k = jst)
            }
        } else if (tid >= 512 && tid < 768) {
            if (it >= 1) {
                float gi = g1buf[bst][jst]       + bi;
                float gf = g1buf[bst][64 + jst]  + bff;
                float gg = g1buf[bst][128 + jst] + bg;
                float go = g1buf[bst][192 + jst] + bo;
                float cc = sigf(gf) * cst + sigf(gi) * tanhf_(gg);
                cst = cc;
                float hh = sigf(go) * tanhf_(cc);
                u1[bst][2 + (jst >> 5)][jst & 31] = hh;  // k = 64 + jst
            }
        }
        if (havex) {
            int t2 = tid - 768, b = t2 >> 5, k = t2 & 31;
            vin[b][k] = xpre;
        }
        __syncthreads();
    }

    // ---- final FC on h1[T-1] ----
    if (tid < NB) {
        float s = bfc[0];
#pragma unroll
        for (int k = 0; k < H; ++k)
            s += u1[tid][2 + (k >> 5)][k & 31] * Wfc[k];
        out[b0 + tid] = s;
    }
}

extern "C" void kernel_launch(void* const* d_in, const int* in_sizes, int n_in,
                              void* d_out, int out_size, void* d_ws, size_t ws_size,
                              hipStream_t stream) {
    const float* x    = (const float*)d_in[0];
    const float* Wih0 = (const float*)d_in[1];
    const float* Whh0 = (const float*)d_in[2];
    const float* bih0 = (const float*)d_in[3];
    const float* bhh0 = (const float*)d_in[4];
    const float* Wih1 = (const float*)d_in[5];
    const float* Whh1 = (const float*)d_in[6];
    const float* bih1 = (const float*)d_in[7];
    const float* bhh1 = (const float*)d_in[8];
    const float* Wfc  = (const float*)d_in[9];
    const float* bfc  = (const float*)d_in[10];
    float* out = (float*)d_out;

    const int B = out_size;            // 1024
    dim3 grid(B / NB), block(1024);
    hipLaunchKernelGGL(lstm2_fused, grid, block, 0, stream,
                       x, Wih0, Whh0, bih0, bhh0,
                       Wih1, Whh1, bih1, bhh1, Wfc, bfc, out);
}